// Round 1
// baseline (257.204 us; speedup 1.0000x reference)
//
#include <hip/hip_runtime.h>

#define B_DIM 4
#define T_DIM 4096
#define C_DIM 2048
#define KK 4
#define TT 32          // t-steps per thread; halo overhead = 3/32
#define C4 (C_DIM / 4) // 512 float4 lanes across channels

__global__ __launch_bounds__(256) void canonconv_kernel(
    const float* __restrict__ x,
    const float* __restrict__ w,
    const float* __restrict__ bias,
    float* __restrict__ out)
{
    const int idx   = blockIdx.x * blockDim.x + threadIdx.x;
    const int c4    = idx % C4;            // which float4 channel group
    const int tmp   = idx / C4;            // uniform across a block (C4=512, block=256 divides evenly)
    const int ttile = tmp % (T_DIM / TT);
    const int b     = tmp / (T_DIM / TT);
    const int t0    = ttile * TT;
    const int c     = c4 * 4;

    // --- load weights for channels c..c+3 (16 contiguous floats), transpose to per-tap vectors
    const float4* wv = (const float4*)(w + (size_t)c * KK);
    const float4 a0 = wv[0];  // (w[c,0], w[c,1], w[c,2], w[c,3])
    const float4 a1 = wv[1];
    const float4 a2 = wv[2];
    const float4 a3 = wv[3];
    const float4 tap0 = make_float4(a0.x, a1.x, a2.x, a3.x); // x[t-3]
    const float4 tap1 = make_float4(a0.y, a1.y, a2.y, a3.y); // x[t-2]
    const float4 tap2 = make_float4(a0.z, a1.z, a2.z, a3.z); // x[t-1]
    // tap3 fused with residual: coefficient on x[t] is (1 + w[c,3])
    const float4 tap3 = make_float4(1.0f + a0.w, 1.0f + a1.w, 1.0f + a2.w, 1.0f + a3.w);
    const float4 bv = *(const float4*)(bias + c);

    const float* xb = x   + ((size_t)b * T_DIM) * C_DIM + c;
    float*       ob = out + ((size_t)b * T_DIM) * C_DIM + c;

    // --- preload 3-deep halo (zeros before t=0; branch is block-uniform)
    float4 xm3, xm2, xm1;
    if (t0 == 0) {
        xm3 = make_float4(0.f, 0.f, 0.f, 0.f);
        xm2 = xm3;
        xm1 = xm3;
    } else {
        xm3 = *(const float4*)(xb + (size_t)(t0 - 3) * C_DIM);
        xm2 = *(const float4*)(xb + (size_t)(t0 - 2) * C_DIM);
        xm1 = *(const float4*)(xb + (size_t)(t0 - 1) * C_DIM);
    }

    #pragma unroll 4
    for (int i = 0; i < TT; ++i) {
        const size_t off = (size_t)(t0 + i) * C_DIM;
        const float4 xc = *(const float4*)(xb + off);
        float4 r;
        r.x = fmaf(xc.x, tap3.x, fmaf(xm1.x, tap2.x, fmaf(xm2.x, tap1.x, fmaf(xm3.x, tap0.x, bv.x))));
        r.y = fmaf(xc.y, tap3.y, fmaf(xm1.y, tap2.y, fmaf(xm2.y, tap1.y, fmaf(xm3.y, tap0.y, bv.y))));
        r.z = fmaf(xc.z, tap3.z, fmaf(xm1.z, tap2.z, fmaf(xm2.z, tap1.z, fmaf(xm3.z, tap0.z, bv.z))));
        r.w = fmaf(xc.w, tap3.w, fmaf(xm1.w, tap2.w, fmaf(xm2.w, tap1.w, fmaf(xm3.w, tap0.w, bv.w))));
        *(float4*)(ob + off) = r;
        xm3 = xm2;
        xm2 = xm1;
        xm1 = xc;
    }
}

extern "C" void kernel_launch(void* const* d_in, const int* in_sizes, int n_in,
                              void* d_out, int out_size, void* d_ws, size_t ws_size,
                              hipStream_t stream) {
    const float* x    = (const float*)d_in[0];
    const float* w    = (const float*)d_in[1];
    const float* bias = (const float*)d_in[2];
    float* out = (float*)d_out;

    const int total_threads = B_DIM * (T_DIM / TT) * C4; // 4*128*512 = 262144
    const int block = 256;
    const int grid  = total_threads / block;             // 1024
    canonconv_kernel<<<grid, block, 0, stream>>>(x, w, bias, out);
}

// Round 2
// 239.893 us; speedup vs baseline: 1.0722x; 1.0722x over previous
//
#include <hip/hip_runtime.h>

#define B_DIM 4
#define T_DIM 4096
#define C_DIM 2048
#define KK 4
#define TT 16          // t-steps per thread; halo overhead = 3/16 (L2/L3-absorbed)
#define C4 (C_DIM / 4) // 512 float4 lanes across channels

typedef float v4f __attribute__((ext_vector_type(4)));

__global__ __launch_bounds__(256) void canonconv_kernel(
    const float* __restrict__ x,
    const float* __restrict__ w,
    const float* __restrict__ bias,
    float* __restrict__ out)
{
    const int idx   = blockIdx.x * blockDim.x + threadIdx.x;
    const int c4    = idx % C4;            // which float4 channel group
    const int tmp   = idx / C4;            // block-uniform (C4=512, block=256 divides evenly)
    const int ttile = tmp % (T_DIM / TT);
    const int b     = tmp / (T_DIM / TT);
    const int t0    = ttile * TT;
    const int c     = c4 * 4;

    // --- load weights for channels c..c+3 (16 contiguous floats), transpose to per-tap vectors
    const v4f* wv = (const v4f*)(w + (size_t)c * KK);
    const v4f a0 = wv[0];  // (w[c,0], w[c,1], w[c,2], w[c,3])
    const v4f a1 = wv[1];
    const v4f a2 = wv[2];
    const v4f a3 = wv[3];
    v4f tap0, tap1, tap2, tap3;
    tap0.x = a0.x; tap0.y = a1.x; tap0.z = a2.x; tap0.w = a3.x; // coeff on x[t-3]
    tap1.x = a0.y; tap1.y = a1.y; tap1.z = a2.y; tap1.w = a3.y; // x[t-2]
    tap2.x = a0.z; tap2.y = a1.z; tap2.z = a2.z; tap2.w = a3.z; // x[t-1]
    // tap on x[t] fused with residual: (1 + w[c,3])
    tap3.x = 1.0f + a0.w; tap3.y = 1.0f + a1.w; tap3.z = 1.0f + a2.w; tap3.w = 1.0f + a3.w;
    const v4f bv = *(const v4f*)(bias + c);

    const float* xb = x   + ((size_t)b * T_DIM) * C_DIM + c;
    float*       ob = out + ((size_t)b * T_DIM) * C_DIM + c;

    // --- preload 3-deep halo (zeros before t=0; branch is block-uniform)
    v4f xm3, xm2, xm1;
    if (t0 == 0) {
        xm3 = (v4f)0.0f;
        xm2 = (v4f)0.0f;
        xm1 = (v4f)0.0f;
    } else {
        xm3 = *(const v4f*)(xb + (size_t)(t0 - 3) * C_DIM);
        xm2 = *(const v4f*)(xb + (size_t)(t0 - 2) * C_DIM);
        xm1 = *(const v4f*)(xb + (size_t)(t0 - 1) * C_DIM);
    }

    #pragma unroll 8
    for (int i = 0; i < TT; ++i) {
        const size_t off = (size_t)(t0 + i) * C_DIM;
        const v4f xc = *(const v4f*)(xb + off);
        v4f r;
        r.x = fmaf(xc.x, tap3.x, fmaf(xm1.x, tap2.x, fmaf(xm2.x, tap1.x, fmaf(xm3.x, tap0.x, bv.x))));
        r.y = fmaf(xc.y, tap3.y, fmaf(xm1.y, tap2.y, fmaf(xm2.y, tap1.y, fmaf(xm3.y, tap0.y, bv.y))));
        r.z = fmaf(xc.z, tap3.z, fmaf(xm1.z, tap2.z, fmaf(xm2.z, tap1.z, fmaf(xm3.z, tap0.z, bv.z))));
        r.w = fmaf(xc.w, tap3.w, fmaf(xm1.w, tap2.w, fmaf(xm2.w, tap1.w, fmaf(xm3.w, tap0.w, bv.w))));
        __builtin_nontemporal_store(r, (v4f*)(ob + off));
        xm3 = xm2;
        xm2 = xm1;
        xm1 = xc;
    }
}

extern "C" void kernel_launch(void* const* d_in, const int* in_sizes, int n_in,
                              void* d_out, int out_size, void* d_ws, size_t ws_size,
                              hipStream_t stream) {
    const float* x    = (const float*)d_in[0];
    const float* w    = (const float*)d_in[1];
    const float* bias = (const float*)d_in[2];
    float* out = (float*)d_out;

    const int total_threads = B_DIM * (T_DIM / TT) * C4; // 4*256*512 = 524288
    const int block = 256;
    const int grid  = total_threads / block;             // 2048
    canonconv_kernel<<<grid, block, 0, stream>>>(x, w, bias, out);
}

// Round 3
// 237.513 us; speedup vs baseline: 1.0829x; 1.0100x over previous
//
#include <hip/hip_runtime.h>

#define B_DIM 4
#define T_DIM 4096
#define C_DIM 2048
#define KK 4
#define TT 16          // t-steps per thread; halo overhead = 3/16 (L2/L3-absorbed)
#define CH 8           // batched-load chunk: 8 loads in flight -> 32 VGPRs of data
#define C4 (C_DIM / 4) // 512 float4 lanes across channels

typedef float v4f __attribute__((ext_vector_type(4)));

__global__ __launch_bounds__(256) void canonconv_kernel(
    const float* __restrict__ x,
    const float* __restrict__ w,
    const float* __restrict__ bias,
    float* __restrict__ out)
{
    const int idx   = blockIdx.x * blockDim.x + threadIdx.x;
    const int c4    = idx % C4;            // which float4 channel group
    const int tmp   = idx / C4;            // block-uniform (C4=512, block=256 divides evenly)
    const int ttile = tmp % (T_DIM / TT);
    const int b     = tmp / (T_DIM / TT);
    const int t0    = ttile * TT;
    const int c     = c4 * 4;

    // --- load weights for channels c..c+3 (16 contiguous floats), transpose to per-tap vectors
    const v4f* wv = (const v4f*)(w + (size_t)c * KK);
    const v4f a0 = wv[0];  // (w[c,0], w[c,1], w[c,2], w[c,3])
    const v4f a1 = wv[1];
    const v4f a2 = wv[2];
    const v4f a3 = wv[3];
    v4f tap0, tap1, tap2, tap3;
    tap0.x = a0.x; tap0.y = a1.x; tap0.z = a2.x; tap0.w = a3.x; // coeff on x[t-3]
    tap1.x = a0.y; tap1.y = a1.y; tap1.z = a2.y; tap1.w = a3.y; // x[t-2]
    tap2.x = a0.z; tap2.y = a1.z; tap2.z = a2.z; tap2.w = a3.z; // x[t-1]
    // tap on x[t] fused with residual: (1 + w[c,3])
    tap3.x = 1.0f + a0.w; tap3.y = 1.0f + a1.w; tap3.z = 1.0f + a2.w; tap3.w = 1.0f + a3.w;
    const v4f bv = *(const v4f*)(bias + c);

    const float* xb = x   + ((size_t)b * T_DIM) * C_DIM + c;
    float*       ob = out + ((size_t)b * T_DIM) * C_DIM + c;

    // --- preload 3-deep halo (zeros before t=0; branch is block-uniform)
    v4f xm3, xm2, xm1;
    if (t0 == 0) {
        xm3 = (v4f)0.0f;
        xm2 = (v4f)0.0f;
        xm1 = (v4f)0.0f;
    } else {
        xm3 = *(const v4f*)(xb + (size_t)(t0 - 3) * C_DIM);
        xm2 = *(const v4f*)(xb + (size_t)(t0 - 2) * C_DIM);
        xm1 = *(const v4f*)(xb + (size_t)(t0 - 1) * C_DIM);
    }

    #pragma unroll
    for (int chnk = 0; chnk < TT / CH; ++chnk) {
        const int tbase = t0 + chnk * CH;
        // Phase 1: batch-issue CH independent loads (forces MLP=CH per wave)
        v4f buf[CH];
        #pragma unroll
        for (int j = 0; j < CH; ++j) {
            buf[j] = *(const v4f*)(xb + (size_t)(tbase + j) * C_DIM);
        }
        // Phase 2: compute + store
        #pragma unroll
        for (int j = 0; j < CH; ++j) {
            const v4f xc = buf[j];
            v4f r;
            r.x = fmaf(xc.x, tap3.x, fmaf(xm1.x, tap2.x, fmaf(xm2.x, tap1.x, fmaf(xm3.x, tap0.x, bv.x))));
            r.y = fmaf(xc.y, tap3.y, fmaf(xm1.y, tap2.y, fmaf(xm2.y, tap1.y, fmaf(xm3.y, tap0.y, bv.y))));
            r.z = fmaf(xc.z, tap3.z, fmaf(xm1.z, tap2.z, fmaf(xm2.z, tap1.z, fmaf(xm3.z, tap0.z, bv.z))));
            r.w = fmaf(xc.w, tap3.w, fmaf(xm1.w, tap2.w, fmaf(xm2.w, tap1.w, fmaf(xm3.w, tap0.w, bv.w))));
            __builtin_nontemporal_store(r, (v4f*)(ob + (size_t)(tbase + j) * C_DIM));
            xm3 = xm2;
            xm2 = xm1;
            xm1 = xc;
        }
    }
}

extern "C" void kernel_launch(void* const* d_in, const int* in_sizes, int n_in,
                              void* d_out, int out_size, void* d_ws, size_t ws_size,
                              hipStream_t stream) {
    const float* x    = (const float*)d_in[0];
    const float* w    = (const float*)d_in[1];
    const float* bias = (const float*)d_in[2];
    float* out = (float*)d_out;

    const int total_threads = B_DIM * (T_DIM / TT) * C4; // 4*256*512 = 524288
    const int block = 256;
    const int grid  = total_threads / block;             // 2048
    canonconv_kernel<<<grid, block, 0, stream>>>(x, w, bias, out);
}